// Round 1
// baseline (204.050 us; speedup 1.0000x reference)
//
#include <hip/hip_runtime.h>
#include <math.h>

#define EPS_COV 1e-6

// ws layout: double[0] = quad accumulator, double[1] = logdet,
// then floats: setup[0..15] = mu_post, setup[16..23] = S00 per block,
// setup[24..31] = 2*S01 per block, setup[32..39] = S11 per block.

__global__ void setup_kernel(const float* __restrict__ mu_like,
                             const float* __restrict__ pose,
                             const float* __restrict__ sp_prior,
                             const float* __restrict__ sp_like,
                             double* __restrict__ wsd,
                             float* __restrict__ setup)
{
    if (blockIdx.x != 0 || threadIdx.x != 0) return;
    wsd[0] = 0.0;  // zero accumulator (ws is poisoned 0xAA before every call)

    // centroid of interleaved (x,y) points
    double cx = 0.0, cy = 0.0;
    for (int i = 0; i < 8; ++i) { cx += (double)mu_like[2*i]; cy += (double)mu_like[2*i+1]; }
    cx *= 0.125; cy *= 0.125;
    double th = (double)pose[2], ct = cos(th), st = sin(th);
    double tx = (double)pose[0], ty = (double)pose[1];

    double logdet = 0.0;
    for (int n = 0; n < 8; ++n) {
        // mu_prior block: rotate about centroid, translate
        double px = (double)mu_like[2*n]   - cx;
        double py = (double)mu_like[2*n+1] - cy;
        double mp0 = ct*px - st*py + tx;
        double mp1 = st*px + ct*py + ty;

        // prior block covariance S = B B^T + eps I, then precision
        const float* p = sp_prior + 4*n;
        double s00 = (double)p[0]*p[0] + (double)p[1]*p[1] + EPS_COV;
        double s01 = (double)p[0]*p[2] + (double)p[1]*p[3];
        double s11 = (double)p[2]*p[2] + (double)p[3]*p[3] + EPS_COV;
        double det = s00*s11 - s01*s01;
        double Pp00 = s11/det, Pp01 = -s01/det, Pp11 = s00/det;

        // likelihood block precision
        const float* l = sp_like + 4*n;
        double t00 = (double)l[0]*l[0] + (double)l[1]*l[1] + EPS_COV;
        double t01 = (double)l[0]*l[2] + (double)l[1]*l[3];
        double t11 = (double)l[2]*l[2] + (double)l[3]*l[3] + EPS_COV;
        double dl = t00*t11 - t01*t01;
        double Pl00 = t11/dl, Pl01 = -t01/dl, Pl11 = t00/dl;

        // posterior precision and its inverse (Sigma_post block)
        double Q00 = Pp00 + Pl00, Q01 = Pp01 + Pl01, Q11 = Pp11 + Pl11;
        double dq = Q00*Q11 - Q01*Q01;
        logdet += log(dq);  // logdet of posterior precision
        double S00 = Q11/dq, S01 = -Q01/dq, S11v = Q00/dq;

        // mu_post block = Sigma_post @ (P_prior@mu_prior + P_like@mu_like)
        double ml0 = (double)mu_like[2*n], ml1 = (double)mu_like[2*n+1];
        double v0 = Pp00*mp0 + Pp01*mp1 + Pl00*ml0 + Pl01*ml1;
        double v1 = Pp01*mp0 + Pp11*mp1 + Pl01*ml0 + Pl11*ml1;
        setup[2*n]   = (float)(S00*v0 + S01*v1);
        setup[2*n+1] = (float)(S01*v0 + S11v*v1);

        setup[16+n] = (float)S00;
        setup[24+n] = (float)(2.0*S01);
        setup[32+n] = (float)S11v;
    }
    wsd[1] = logdet;
}

__global__ __launch_bounds__(256) void quad_kernel(
    const float4* __restrict__ obs4,
    const float*  __restrict__ setup,
    double* __restrict__ acc,
    int n4)
{
    const int tid    = blockIdx.x * blockDim.x + threadIdx.x;
    const int stride = gridDim.x * blockDim.x;   // multiple of 4 -> q loop-invariant
    const int q = tid & 3;

    // per-quarter coefficients: mu[4q..4q+3], blocks 2q and 2q+1
    const float m0 = setup[4*q+0], m1 = setup[4*q+1];
    const float m2 = setup[4*q+2], m3 = setup[4*q+3];
    const float a0 = setup[16+2*q],   b0 = setup[24+2*q],   c0 = setup[32+2*q];
    const float a1 = setup[16+2*q+1], b1 = setup[24+2*q+1], c1 = setup[32+2*q+1];

    double accd = 0.0;
    #pragma unroll 4
    for (int i = tid; i < n4; i += stride) {
        float4 v = obs4[i];
        float d0 = v.x - m0, d1 = v.y - m1;
        float d2 = v.z - m2, d3 = v.w - m3;
        float pq = a0*d0*d0 + b0*d0*d1 + c0*d1*d1
                 + a1*d2*d2 + b1*d2*d3 + c1*d3*d3;
        accd += (double)pq;
    }

    // wave (64-lane) butterfly reduce
    #pragma unroll
    for (int off = 32; off > 0; off >>= 1)
        accd += __shfl_down(accd, off, 64);

    __shared__ double lds[4];  // 256 threads = 4 waves
    const int wave = threadIdx.x >> 6;
    if ((threadIdx.x & 63) == 0) lds[wave] = accd;
    __syncthreads();
    if (threadIdx.x == 0) {
        double s = lds[0] + lds[1] + lds[2] + lds[3];
        atomicAdd(acc, s);
    }
}

__global__ void finalize_kernel(const double* __restrict__ wsd,
                                float* __restrict__ out,
                                double n_obs)
{
    if (blockIdx.x != 0 || threadIdx.x != 0) return;
    const double LOG_2PI = 1.8378770664093454835606594728112;
    double c = n_obs * (16.0 * LOG_2PI + 0.5 * wsd[1]);
    out[0] = (float)(c + 0.5 * wsd[0]);
}

extern "C" void kernel_launch(void* const* d_in, const int* in_sizes, int n_in,
                              void* d_out, int out_size, void* d_ws, size_t ws_size,
                              hipStream_t stream) {
    const float* obs      = (const float*)d_in[0];
    const float* mu_like  = (const float*)d_in[1];
    const float* pose     = (const float*)d_in[2];
    const float* sp_prior = (const float*)d_in[3];
    const float* sp_like  = (const float*)d_in[4];
    float* out = (float*)d_out;

    double* wsd  = (double*)d_ws;
    float* setup = (float*)((char*)d_ws + 2 * sizeof(double));

    const int n_elems = in_sizes[0];        // 32,000,000
    const int n4      = n_elems / 4;        // 8,388,608 float4s
    const double n_obs = (double)(n_elems / 16);

    setup_kernel<<<1, 64, 0, stream>>>(mu_like, pose, sp_prior, sp_like, wsd, setup);

    const int threads = 256;
    const int blocks  = 2048;               // 512K threads, 16 float4/thread
    quad_kernel<<<blocks, threads, 0, stream>>>((const float4*)obs, setup, wsd, n4);

    finalize_kernel<<<1, 64, 0, stream>>>(wsd, out, n_obs);
}